// Round 7
// baseline (252.239 us; speedup 1.0000x reference)
//
#include <hip/hip_runtime.h>
#include <hip/hip_bf16.h>

// SAGE reranker, round 16: L2-resident gather via dim-split.
// R15: combines ~38us each, FETCH 46MB = 8 XCDs x 6.4MB -> every XCD pulls
// the whole q8 array past its 4MB L2; random reads miss at ~900cy. Fix:
// split the fp8 aggregate into q8lo/q8hi [N+1][64] (3.2MB each, L2-fits).
// Each combine = two temporal passes (one grid: lo-blocks then hi-blocks;
// dispatch order separates the working sets). Pass gathers 64B rows, 64
// lanes x 1 byte; decode packs 2 neighbors' bytes per cvt_pk_f32_fp8
// (acc += f[0]+f[1]) so VALU/byte stays ~flat. R11 gather skeleton kept:
// 2-node interleave, 16-deep batches, wave-uniform guards, readfirstlane.
// GEMM epilogues split fp8 stores lo/hi; lane d owns dim half*64+d.

#define DIN 256
#define DH 128
#define NPB 256
#define LOG_NPB 8
#define NBMAX 256
#define EPB 2048
#define JL (EPB/256)
#define SLOTS 8192

typedef __attribute__((ext_vector_type(8))) short short8;
typedef __attribute__((ext_vector_type(4))) float float4v;
typedef __attribute__((ext_vector_type(2))) float float2v;

__device__ inline ushort f2b(float f){
  unsigned u = __float_as_uint(f);
  u = (u + 0x7fffu + ((u >> 16) & 1u)) >> 16;   // round-nearest-even
  return (ushort)u;
}
__device__ inline float blo(unsigned v){ return __uint_as_float(v << 16); }
__device__ inline float bhi(unsigned v){ return __uint_as_float(v & 0xffff0000u); }
__device__ inline float b2f(ushort v){ return __uint_as_float(((unsigned)v) << 16); }
__device__ inline short8 pack8(float4 f0, float4 f1){
  short8 v;
  v[0]=(short)f2b(f0.x); v[1]=(short)f2b(f0.y); v[2]=(short)f2b(f0.z); v[3]=(short)f2b(f0.w);
  v[4]=(short)f2b(f1.x); v[5]=(short)f2b(f1.y); v[6]=(short)f2b(f1.z); v[7]=(short)f2b(f1.w);
  return v;
}
__device__ inline void glds16(const ushort* g, ushort* l){
  __builtin_amdgcn_global_load_lds((const __attribute__((address_space(1))) void*)g,
                                   (__attribute__((address_space(3))) void*)l, 16, 0, 0);
}
// fp8 e4m3 (OCP on gfx950) encode/decode via HW converts
__device__ inline unsigned char enc8(float v){
  return (unsigned char)(__builtin_amdgcn_cvt_pk_fp8_f32(v, v, 0, false) & 0xFF);
}
__device__ inline float2v dec8(unsigned u){
  return __builtin_amdgcn_cvt_pk_f32_fp8((int)u, false);   // decodes low 2 bytes
}

// Interleaved 2-node byte-gather over a [*][64] fp8 array (one dim-half).
// Lane d owns dim d of the half. Padded CSR (pdeg multiple of 16, pads ->
// zero row). Issue A's 16 byte-loads, B's 16, then decode A, B: two
// neighbors' bytes packed per cvt (acc += f[0]+f[1]). Guards wave-uniform;
// row indices via readfirstlane -> scalar address pipe.
__device__ inline void gather16x2b(const unsigned char* __restrict__ a8,
    const ushort* __restrict__ adj, int pA, int eA, int pB, int eB, int lane,
    float& aA, float& aB)
{
  while (pA < eA || pB < eB){
    unsigned char uA[16], uB[16];
    bool dA = pA < eA, dB = pB < eB;
    if (dA){
      #pragma unroll
      for (int j=0;j<16;j++){
        int ix = __builtin_amdgcn_readfirstlane((int)adj[pA+j]);
        uA[j] = a8[(size_t)ix*64 + lane];
      }
    }
    if (dB){
      #pragma unroll
      for (int j=0;j<16;j++){
        int ix = __builtin_amdgcn_readfirstlane((int)adj[pB+j]);
        uB[j] = a8[(size_t)ix*64 + lane];
      }
    }
    if (dA){
      #pragma unroll
      for (int j=0;j<8;j++){
        unsigned u = (unsigned)uA[2*j] | ((unsigned)uA[2*j+1] << 8);
        float2v f = dec8(u);
        aA += f[0] + f[1];
      }
      pA += 16;
    }
    if (dB){
      #pragma unroll
      for (int j=0;j<8;j++){
        unsigned u = (unsigned)uB[2*j] | ((unsigned)uB[2*j+1] << 8);
        float2v f = dec8(u);
        aB += f[0] + f[1];
      }
      pB += 16;
    }
  }
}

// ================= L1: fused front: [partition | convert-x stripe-frag | weight prep] ===========
__global__ __launch_bounds__(256) void fused_front(
    const float* __restrict__ x, int N, ushort* __restrict__ xb, int nstripe,
    const float* __restrict__ Wp, const float* __restrict__ Wl0, const float* __restrict__ Wr0,
    const float* __restrict__ Wl1, const float* __restrict__ Wr1, const float* __restrict__ W1,
    ushort* __restrict__ Wpf, ushort* __restrict__ Wl0f, ushort* __restrict__ Wr0f,
    ushort* __restrict__ Wl1f, ushort* __restrict__ Wr1f, ushort* __restrict__ W1f,
    const int* __restrict__ src, const int* __restrict__ dst, int E, int NB,
    int* __restrict__ bucketCnt, int* __restrict__ pairS, int* __restrict__ pairD,
    int nPart, int nConv)
{
  __shared__ int hist[NBMAX], lbase[NBMAX], gbase[NBMAX], lcur[NBMAX], sc[NBMAX];
  __shared__ int ls[EPB], ld[EPB];
  int bid = blockIdx.x;
  int t = threadIdx.x;

  if (bid < nPart){
    int base = bid * EPB;
    int cntE = E - base; if (cntE > EPB) cntE = EPB;
    for (int i=t;i<NB;i+=256) hist[i]=0;
    __syncthreads();
    int myS[JL], myD[JL];
    #pragma unroll
    for (int j=0;j<JL;j++){
      int e = base + j*256 + t;
      if (e < E){ myS[j]=src[e]; myD[j]=dst[e]; atomicAdd(&hist[myD[j]>>LOG_NPB],1); }
      else myD[j] = -1;
    }
    __syncthreads();
    if (t < NBMAX) sc[t] = (t < NB)? hist[t] : 0;
    __syncthreads();
    for (int st=1; st<NBMAX; st<<=1){
      int v = 0;
      if (t < NBMAX && t >= st) v = sc[t-st];
      __syncthreads();
      if (t < NBMAX) sc[t] += v;
      __syncthreads();
    }
    if (t < NB){
      int excl = (t>0)? sc[t-1] : 0;
      lbase[t] = excl; lcur[t] = excl;
      gbase[t] = atomicAdd(&bucketCnt[t], hist[t]);
    }
    __syncthreads();
    #pragma unroll
    for (int j=0;j<JL;j++){
      if (myD[j] >= 0){
        int b = myD[j] >> LOG_NPB;
        int p = atomicAdd(&lcur[b], 1);
        ls[p] = myS[j]; ld[p] = myD[j];
      }
    }
    __syncthreads();
    for (int i=t;i<cntE;i+=256){
      int d = ld[i];
      int b = d >> LOG_NPB;
      int p = gbase[b] + (i - lbase[b]);
      if (p < SLOTS){
        pairS[(size_t)b*SLOTS + p] = ls[i];
        pairD[(size_t)b*SLOTS + p] = d;
      }
    }
  } else if (bid < nPart + nConv){
    int gi = (bid - nPart)*256 + t;
    if (gi < nstripe*512){
      int L = gi & 63, ks = (gi>>6)&7, s = gi>>9;
      int row = s*16 + (L&15);
      int k = ks*32 + (L>>4)*8;
      short8 v;
      if (row < N){
        const float* p = x + (size_t)row*DIN + k;
        v = pack8(*(const float4*)p, *(const float4*)(p+4));
      } else {
        #pragma unroll
        for (int j=0;j<8;j++) v[j]=0;
      }
      *(short8*)(xb + (size_t)gi*8) = v;
    }
  } else {
    int gi = (bid - nPart - nConv)*256 + t;
    if (gi < 17408){
      const float* sw; ushort* dw; int cols, b0;
      if      (gi <  4096){ sw=Wp;  dw=Wpf;  cols=128; b0=0; }
      else if (gi <  8192){ sw=Wl0; dw=Wl0f; cols=128; b0=4096; }
      else if (gi < 12288){ sw=Wr0; dw=Wr0f; cols=128; b0=8192; }
      else if (gi < 14336){ sw=Wl1; dw=Wl1f; cols=128; b0=12288; }
      else if (gi < 16384){ sw=Wr1; dw=Wr1f; cols=128; b0=14336; }
      else                { sw=W1;  dw=W1f;  cols=64;  b0=16384; }
      int i = gi - b0;
      int ln = i & 63, g = i >> 6;
      int ntq = cols >> 4;
      int nt = g % ntq, ks = g / ntq;
      int col = nt*16 + (ln & 15);
      int k0 = ks*32 + (ln >> 4)*8;
      short8 v;
      #pragma unroll
      for (int j=0;j<8;j++) v[j] = (short)f2b(sw[(size_t)(k0+j)*cols + col]);
      *(short8*)(dw + (size_t)i*8) = v;
    }
  }
}

// ================= L2: [bucket_csr (padded-to-16, ushort adj) FIRST | GEMM0 wres] =================
__global__ __launch_bounds__(256) void gemm0_csr(
    const ushort* __restrict__ xb, int N, int nstripe, int ngemm, int nbuck,
    const ushort* __restrict__ Wpf, const ushort* __restrict__ Wl0f, const ushort* __restrict__ Wr0f,
    const float* __restrict__ bp,
    ushort* __restrict__ xp, unsigned char* __restrict__ q8lo, unsigned char* __restrict__ q8hi,
    ushort* __restrict__ xr0,
    const int* __restrict__ bucketCnt, const int* __restrict__ pairS, const int* __restrict__ pairD,
    int* __restrict__ off, int* __restrict__ deg, ushort* __restrict__ adj)
{
  __shared__ __align__(16) ushort smem[32768];
  int bid = blockIdx.x, t = threadIdx.x;

  if (bid >= nbuck){
    int g = bid - nbuck;
    int xcd = g & 7, jj = g >> 3;
    int mat = jj % 3;
    int b = xcd + 8*(jj/3);             // 3 mats of chunk-set b share bid%8 -> same XCD
    int nblk = ngemm / 3;
    const ushort* Wf = (mat==0)? Wpf : (mat==1)? Wl0f : Wr0f;
    int w = t>>6, lane = t&63, lq = lane&15, quad = lane>>4;
    #pragma unroll
    for (int j=0;j<16;j++){
      int gg = w + j*4;
      glds16(Wf + (size_t)gg*512 + lane*8, smem + gg*512);
    }
    __syncthreads();
    float bias[8];
    #pragma unroll
    for (int nt=0;nt<8;nt++) bias[nt] = (mat==0)? bp[nt*16 + lq] : 0.f;
    int nchunk = (nstripe + 3) >> 2;

#define LOADAV(AV, cc) do { \
    int stripe_ = (cc)*4 + w; \
    if (stripe_ < nstripe){ \
      _Pragma("unroll") \
      for (int ks=0;ks<8;ks++) \
        AV[ks] = *(const short8*)(xb + ((size_t)stripe_*8 + ks)*512 + lane*8); \
    } \
  } while(0)

#define COMPSTORE(AV, cc) do { \
    int stripe_ = (cc)*4 + w; \
    if (stripe_ < nstripe){ \
      int row0_ = stripe_*16; \
      float4v acc_[8]; \
      _Pragma("unroll") for (int nt=0;nt<8;nt++){ \
        _Pragma("unroll") for (int r=0;r<4;r++) acc_[nt][r]=0.f; } \
      _Pragma("unroll") for (int ks=0;ks<8;ks++){ \
        _Pragma("unroll") for (int nt=0;nt<8;nt++){ \
          short8 bf_ = *(const short8*)(smem + (size_t)((ks*8+nt)*64 + lane)*8); \
          acc_[nt] = __builtin_amdgcn_mfma_f32_16x16x32_bf16(AV[ks], bf_, acc_[nt], 0,0,0); \
        } \
      } \
      if (mat == 1){ \
        _Pragma("unroll") for (int nt=0;nt<8;nt++) \
        _Pragma("unroll") for (int r=0;r<4;r++){ \
          int row_ = row0_ + quad*4 + r; \
          if (row_ < N){ \
            if (nt < 4) q8lo[(size_t)row_*64 + nt*16 + lq] = enc8(acc_[nt][r]); \
            else        q8hi[(size_t)row_*64 + (nt-4)*16 + lq] = enc8(acc_[nt][r]); \
          } \
        } \
      } else { \
        ushort* Y_ = (mat==0)? xp : xr0; \
        _Pragma("unroll") for (int nt=0;nt<8;nt++) \
        _Pragma("unroll") for (int r=0;r<4;r++){ \
          int row_ = row0_ + quad*4 + r; \
          if (row_ < N) Y_[(size_t)row_*128 + nt*16 + lq] = f2b(acc_[nt][r] + bias[nt]); \
        } \
      } \
    } \
  } while(0)

    short8 avA[8], avB[8];
    int c = b;
    if (c < nchunk){
      LOADAV(avA, c);
      while (true){
        int cn = c + nblk;
        if (cn < nchunk) LOADAV(avB, cn);
        COMPSTORE(avA, c);
        c = cn;
        if (c >= nchunk) break;
        cn = c + nblk;
        if (cn < nchunk) LOADAV(avA, cn);
        COMPSTORE(avB, c);
        c = cn;
        if (c >= nchunk) break;
      }
    }
#undef LOADAV
#undef COMPSTORE
  } else {
    // -------- bucket CSR: 256 nodes/bucket, int4-vectorized walks, ushort adj --------
    int b = bid;
    int* cnt  = (int*)smem;             // [256]
    int* offl = cnt + 256;              // [257]
    int* s1   = offl + 257;             // [256]
    ushort* win = (ushort*)(s1 + 256);  // [<= SLOTS]
    int node0 = b * NPB;
    int base  = b * SLOTS;
    int ce = bucketCnt[b]; if (ce > SLOTS) ce = SLOTS;
    int ce4 = ce & ~3;
    cnt[t] = 0;
    __syncthreads();
    for (int i = t*4; i < ce4; i += 1024){
      int4 dd = *(const int4*)(pairD + base + i);
      atomicAdd(&cnt[dd.x - node0], 1);
      atomicAdd(&cnt[dd.y - node0], 1);
      atomicAdd(&cnt[dd.z - node0], 1);
      atomicAdd(&cnt[dd.w - node0], 1);
    }
    for (int i = ce4 + t; i < ce; i += 256)
      atomicAdd(&cnt[pairD[(size_t)base+i] - node0], 1);
    __syncthreads();
    int a = cnt[t];
    int pa = (a + 15) & ~15;         // padded count
    s1[t] = pa;
    __syncthreads();
    for (int st=1; st<256; st<<=1){
      int v = (t>=st)? s1[t-st] : 0;
      __syncthreads();
      s1[t] += v;
      __syncthreads();
    }
    int excl = (t>0)? s1[t-1] : 0;
    offl[t] = excl;
    int ptotal = s1[255]; if (ptotal > SLOTS) ptotal = SLOTS;
    int node = node0 + t;
    if (node < N){ off[node] = base + excl; deg[node] = a; }
    __syncthreads();
    for (int i=t;i<ptotal;i+=256) win[i] = (ushort)N;  // zero-row padding
    __syncthreads();
    for (int i = t*4; i < ce4; i += 1024){
      int4 dd = *(const int4*)(pairD + base + i);
      int4 ss = *(const int4*)(pairS + base + i);
      int p0 = atomicAdd(&offl[dd.x - node0], 1); if (p0 < SLOTS) win[p0] = (ushort)ss.x;
      int p1 = atomicAdd(&offl[dd.y - node0], 1); if (p1 < SLOTS) win[p1] = (ushort)ss.y;
      int p2 = atomicAdd(&offl[dd.z - node0], 1); if (p2 < SLOTS) win[p2] = (ushort)ss.z;
      int p3 = atomicAdd(&offl[dd.w - node0], 1); if (p3 < SLOTS) win[p3] = (ushort)ss.w;
    }
    for (int i = ce4 + t; i < ce; i += 256){
      int dd = pairD[(size_t)base+i];
      int p = atomicAdd(&offl[dd - node0], 1);
      if (p < SLOTS) win[p] = (ushort)pairS[(size_t)base+i];
    }
    __syncthreads();
    for (int i=t;i<ptotal;i+=256) adj[(size_t)base+i] = win[i];
  }
}

// ================= combine (one dim-half): out_half = bf16(relu(mean+bias+root)+res) ========
// Grid = 2*nbh blocks: blocks [0,nbh) gather q8lo (dims 0..63), [nbh,2nbh)
// gather q8hi (dims 64..127). Dispatch order keeps each 3.2MB half L2-hot.
// 2 nodes per wave; no LDS, no barrier.
__global__ __launch_bounds__(256) void combine_f8h(
    const unsigned char* __restrict__ q8lo, const unsigned char* __restrict__ q8hi,
    const ushort* __restrict__ rootsrc, const ushort* __restrict__ ressrc,
    const float* __restrict__ bias,
    const int* __restrict__ off, const int* __restrict__ deg,
    const ushort* __restrict__ adj, ushort* __restrict__ out, int n, int nbh)
{
  int t = threadIdx.x;
  int d = t & 63, w = t >> 6;
  int b = blockIdx.x;
  int half = (b >= nbh) ? 1 : 0;
  int nA = (b - half*nbh)*8 + w*2, nB = nA + 1;
  if (nA >= n) return;
  const unsigned char* a8 = half ? q8hi : q8lo;
  int hd = half*64 + d;
  bool vB = nB < n;
  ushort rtA = rootsrc[(size_t)nA*128 + hd];
  ushort rsA = ressrc[(size_t)nA*128 + hd];
  ushort rtB = 0, rsB = 0;
  int pA = off[nA], cA = deg[nA], eA = pA + ((cA + 15) & ~15);
  int pB = 0, cB = 0, eB = 0;
  if (vB){
    rtB = rootsrc[(size_t)nB*128 + hd];
    rsB = ressrc[(size_t)nB*128 + hd];
    pB = off[nB]; cB = deg[nB]; eB = pB + ((cB + 15) & ~15);
  }
  float aA = 0.f, aB = 0.f;
  gather16x2b(a8, adj, pA, eA, pB, eB, d, aA, aB);
  float bv = bias[hd];
  float invA = 1.f / (float)((cA > 1)? cA : 1);
  float o0 = fmaxf(aA*invA + bv + b2f(rtA), 0.f) + b2f(rsA);
  out[(size_t)nA*128 + hd] = f2b(o0);
  if (vB){
    float invB = 1.f / (float)((cB > 1)? cB : 1);
    float o1 = fmaxf(aB*invB + bv + b2f(rtB), 0.f) + b2f(rsB);
    out[(size_t)nB*128 + hd] = f2b(o1);
  }
}

// ================= GEMM1: weights-resident; hl1 output fp8 (lo/hi), hr1 bf16 =================
__global__ __launch_bounds__(256) void gemm1_wres(
    const ushort* __restrict__ h, int N,
    const ushort* __restrict__ Wl1f, const ushort* __restrict__ Wr1f,
    unsigned char* __restrict__ q8lo, unsigned char* __restrict__ q8hi,
    ushort* __restrict__ hr1)
{
  __shared__ __align__(16) ushort Bs[32768];
  int t = threadIdx.x, w = t>>6, lane = t&63, lq = lane&15, quad = lane>>4;
  int tile = blockIdx.x;
  #pragma unroll
  for (int j=0;j<16;j++){
    int r = w + j*4;
    int m = r>>5, g = r&31;
    const ushort* Wm = m ? Wr1f : Wl1f;
    glds16(Wm + (size_t)g*512 + lane*8, Bs + r*512);
  }
  short8 av[2][4];
  int row0 = tile*128 + w*32;
  #pragma unroll
  for (int mt=0;mt<2;mt++){
    int row = row0 + mt*16 + lq; if (row >= N) row = N-1;
    #pragma unroll
    for (int ks=0;ks<4;ks++)
      av[mt][ks] = *(const short8*)(h + (size_t)row*128 + ks*32 + quad*8);
  }
  __syncthreads();
  #pragma unroll
  for (int m=0;m<2;m++){
    float4v acc[2][8];
    #pragma unroll
    for (int i=0;i<2;i++)
      #pragma unroll
      for (int j=0;j<8;j++)
        #pragma unroll
        for (int r=0;r<4;r++) acc[i][j][r] = 0.f;
    #pragma unroll
    for (int ks=0;ks<4;ks++){
      #pragma unroll
      for (int nt=0;nt<8;nt++){
        short8 bf = *(const short8*)(Bs + ((m*32 + ks*8 + nt)*64 + lane)*8);
        acc[0][nt] = __builtin_amdgcn_mfma_f32_16x16x32_bf16(av[0][ks], bf, acc[0][nt], 0,0,0);
        acc[1][nt] = __builtin_amdgcn_mfma_f32_16x16x32_bf16(av[1][ks], bf, acc[1][nt], 0,0,0);
      }
    }
    #pragma unroll
    for (int mt=0;mt<2;mt++){
      #pragma unroll
      for (int r=0;r<4;r++){
        int row = row0 + mt*16 + quad*4 + r;
        if (row < N){
          if (m == 0){
            #pragma unroll
            for (int nt=0;nt<8;nt++){
              if (nt < 4) q8lo[(size_t)row*64 + nt*16 + lq] = enc8(acc[mt][nt][r]);
              else        q8hi[(size_t)row*64 + (nt-4)*16 + lq] = enc8(acc[mt][nt][r]);
            }
          } else {
            #pragma unroll
            for (int nt=0;nt<8;nt++)
              hr1[(size_t)row*128 + nt*16 + lq] = f2b(acc[mt][nt][r]);
          }
        }
      }
    }
  }
}

// ================= head MLP: out = a*rer + (1-a)*(relu(h2@W1+b1)@W2+b2) =================
__global__ __launch_bounds__(256) void head_mlp(
    const ushort* __restrict__ h2, int n,
    const ushort* __restrict__ W1f, const float* __restrict__ b1,
    const float* __restrict__ W2, const float* __restrict__ b2,
    const float* __restrict__ alogit, const float* __restrict__ rer,
    float* __restrict__ out)
{
  __shared__ __align__(16) ushort W1s[8192];
  int t = threadIdx.x, w = t>>6, lane = t&63, lq = lane&15, quad = lane>>4;
  #pragma unroll
  for (int j=0;j<4;j++){
    int g = w + j*4;
    glds16(W1f + (size_t)g*512 + lane*8, W1s + g*512);
  }
  int row0 = blockIdx.x*128 + w*32;
  short8 av[2][4];
  #pragma unroll
  for (int mt=0;mt<2;mt++){
    int row = row0 + mt*16 + lq; if (row >= n) row = n-1;
    #pragma unroll
    for (int ks=0;ks<4;ks++)
      av[mt][ks] = *(const short8*)(h2 + (size_t)row*128 + ks*32 + quad*8);
  }
  __syncthreads();
  float4v acc[2][4];
  #pragma unroll
  for (int mt=0;mt<2;mt++)
    #pragma unroll
    for (int nt=0;nt<4;nt++)
      #pragma unroll
      for (int r=0;r<4;r++) acc[mt][nt][r] = 0.f;
  #pragma unroll
  for (int ks=0;ks<4;ks++){
    #pragma unroll
    for (int nt=0;nt<4;nt++){
      short8 bf = *(const short8*)(W1s + ((ks*4 + nt)*64 + lane)*8);
      acc[0][nt] = __builtin_amdgcn_mfma_f32_16x16x32_bf16(av[0][ks], bf, acc[0][nt], 0,0,0);
      acc[1][nt] = __builtin_amdgcn_mfma_f32_16x16x32_bf16(av[1][ks], bf, acc[1][nt], 0,0,0);
    }
  }
  float al = alogit[0];
  float a  = 1.f / (1.f + __expf(-al));
  #pragma unroll
  for (int mt=0;mt<2;mt++){
    float pw[4] = {0.f,0.f,0.f,0.f};
    #pragma unroll
    for (int nt=0; nt<4; nt++){
      int c = nt*16 + lq;
      float w2 = W2[c];
      float bb = b1[c];
      #pragma unroll
      for (int r=0; r<4; r++)
        pw[r] += fmaxf(acc[mt][nt][r] + bb, 0.f) * w2;
    }
    #pragma unroll
    for (int mask=1; mask<16; mask<<=1){
      #pragma unroll
      for (int r=0; r<4; r++)
        pw[r] += __shfl_xor(pw[r], mask);
    }
    if (lq == 0){
      #pragma unroll
      for (int r=0; r<4; r++){
        int row = row0 + mt*16 + quad*4 + r;
        if (row < n)
          out[row] = a * rer[row] + (1.f - a) * (pw[r] + b2[0]);
      }
    }
  }
}

extern "C" void kernel_launch(void* const* d_in, const int* in_sizes, int n_in,
                              void* d_out, int out_size, void* d_ws, size_t ws_size,
                              hipStream_t stream)
{
  (void)n_in; (void)out_size; (void)ws_size;
  const float* x    = (const float*)d_in[0];
  const int*   ei   = (const int*)d_in[1];
  const float* rer  = (const float*)d_in[2];
  const float* Wp   = (const float*)d_in[3];
  const float* bp   = (const float*)d_in[4];
  const float* Wl0  = (const float*)d_in[5];
  const float* bl0  = (const float*)d_in[6];
  const float* Wr0  = (const float*)d_in[7];
  const float* Wl1  = (const float*)d_in[8];
  const float* bl1  = (const float*)d_in[9];
  const float* Wr1  = (const float*)d_in[10];
  const float* W1   = (const float*)d_in[11];
  const float* b1   = (const float*)d_in[12];
  const float* W2   = (const float*)d_in[13];
  const float* b2   = (const float*)d_in[14];
  const float* alogit = (const float*)d_in[15];

  const int N = in_sizes[2];      // 50000
  const int E = in_sizes[1] / 2;  // 800000
  const int* src = ei;
  const int* dst = ei + E;
  const int NB = (N + NPB - 1) / NPB;        // 196
  const int nstripe = (N + 15) / 16;         // 3125
  const int ntile = (N + 127) / 128;         // 391
  const int nPart = (E + EPB - 1) / EPB;     // 391
  const int nConv = (nstripe*512 + 255)/256; // 6250
  const int nbh = (N + 7) / 8;               // 6250 blocks per dim-half

  // workspace layout (q8lo/q8hi have N+1 rows; row N is the zero row)
  ushort* U = (ushort*)d_ws;
  ushort* xb  = U;                           // stripe-frag x; reused as h2
  ushort* xp  = xb + (size_t)nstripe*512*8;  // [N][128] residual
  ushort* xr0 = xp  + (size_t)N*DH;          // root0; reused as hr1
  ushort* h   = xr0 + (size_t)N*DH;
  unsigned char* q8lo = (unsigned char*)(h + (size_t)N*DH);   // [N+1][64] fp8
  unsigned char* q8hi = q8lo + (size_t)(N+1)*64;              // [N+1][64] fp8
  ushort* Wpf  = (ushort*)(q8hi + (size_t)(N+1)*64);
  ushort* Wl0f = Wpf  + (size_t)4096*8;
  ushort* Wr0f = Wl0f + (size_t)4096*8;
  ushort* Wl1f = Wr0f + (size_t)4096*8;
  ushort* Wr1f = Wl1f + (size_t)2048*8;
  ushort* W1f  = Wr1f + (size_t)2048*8;
  int* I = (int*)(W1f + (size_t)1024*8);
  int* bucketCnt = I;
  int* off   = bucketCnt + NBMAX;
  int* deg   = off + N;
  int* pairS = deg + N;
  int* pairD = pairS + (size_t)NB*SLOTS;
  ushort* adj = (ushort*)(pairD + (size_t)NB*SLOTS);
  ushort* h2  = xb;                          // aliases xb (dead after GEMM0)

  hipMemsetAsync(bucketCnt, 0, NBMAX*sizeof(int), stream);
  hipMemsetAsync(q8lo + (size_t)N*64, 0, 64, stream);   // zero rows for padding
  hipMemsetAsync(q8hi + (size_t)N*64, 0, 64, stream);

  // L1: [partition | convert | prep]
  fused_front<<<nPart + nConv + 68, 256, 0, stream>>>(
      x, N, xb, nstripe, Wp, Wl0, Wr0, Wl1, Wr1, W1,
      Wpf, Wl0f, Wr0f, Wl1f, Wr1f, W1f,
      src, dst, E, NB, bucketCnt, pairS, pairD, nPart, nConv);

  // L2: [bucket_csr FIRST | GEMM0]  (xl0 -> q8lo/q8hi fp8; CSR padded to 16)
  gemm0_csr<<<NB + 768, 256, 0, stream>>>(
      xb, N, nstripe, 768, NB, Wpf, Wl0f, Wr0f, bp, xp, q8lo, q8hi, xr0,
      bucketCnt, pairS, pairD, off, deg, adj);

  // combine0 (two L2-resident passes): h = relu(mean(q8[nbrs]) + bl0 + xr0) + xp
  combine_f8h<<<2*nbh, 256, 0, stream>>>(q8lo, q8hi, xr0, xp, bl0, off, deg, adj, h, N, nbh);

  // GEMM1: hl1 -> q8lo/q8hi (fp8), hr1 -> xr0 (bf16)
  gemm1_wres<<<ntile, 256, 0, stream>>>(h, N, Wl1f, Wr1f, q8lo, q8hi, xr0);

  // combine1 (two passes): h2 = relu(mean(q8[nbrs]) + bl1 + hr1) + h
  combine_f8h<<<2*nbh, 256, 0, stream>>>(q8lo, q8hi, xr0, h, bl1, off, deg, adj, h2, N, nbh);

  // head MLP (dense)
  head_mlp<<<ntile, 256, 0, stream>>>(h2, N, W1f, b1, W2, b2, alogit, rer, (float*)d_out);
}

// Round 9
// 237.840 us; speedup vs baseline: 1.0605x; 1.0605x over previous
//
#include <hip/hip_runtime.h>
#include <hip/hip_bf16.h>

// SAGE reranker, round 18 (= R17 resubmit; container infra failure, no data).
// R16 post-mortem: dim-split made FETCH = compulsory floor (47MB) and occ
// 65%, but two passes DOUBLED per-edge instructions (VALU 70%, 43us/combine
// vs R15's 38). Fix: half-wave row packing. A 64B half-row needs 32 lanes x
// 2B, so one 64-lane load covers TWO neighbors of the same node (lanes 0-31
// -> neighbor 2j, lanes 32-63 -> neighbor 2j+1): 16-neighbor batch = 8 load
// insts; two passes = R15's total issue count at L2-hit latency. Guards stay
// wave-uniform (both half-waves serve the same node; only the neighbor index
// differs). adj via two uniform uint4 loads/batch; addr = v_bfe + v_lshl_add.
// Epilogue: shfl_xor(32) folds half-sums; half-wave 0 writes node A, 1
// writes node B in the same store.

#define DIN 256
#define DH 128
#define NPB 256
#define LOG_NPB 8
#define NBMAX 256
#define EPB 2048
#define JL (EPB/256)
#define SLOTS 8192

typedef __attribute__((ext_vector_type(8))) short short8;
typedef __attribute__((ext_vector_type(4))) float float4v;
typedef __attribute__((ext_vector_type(2))) float float2v;

__device__ inline ushort f2b(float f){
  unsigned u = __float_as_uint(f);
  u = (u + 0x7fffu + ((u >> 16) & 1u)) >> 16;   // round-nearest-even
  return (ushort)u;
}
__device__ inline float blo(unsigned v){ return __uint_as_float(v << 16); }
__device__ inline float bhi(unsigned v){ return __uint_as_float(v & 0xffff0000u); }
__device__ inline float b2f(ushort v){ return __uint_as_float(((unsigned)v) << 16); }
__device__ inline short8 pack8(float4 f0, float4 f1){
  short8 v;
  v[0]=(short)f2b(f0.x); v[1]=(short)f2b(f0.y); v[2]=(short)f2b(f0.z); v[3]=(short)f2b(f0.w);
  v[4]=(short)f2b(f1.x); v[5]=(short)f2b(f1.y); v[6]=(short)f2b(f1.z); v[7]=(short)f2b(f1.w);
  return v;
}
__device__ inline void glds16(const ushort* g, ushort* l){
  __builtin_amdgcn_global_load_lds((const __attribute__((address_space(1))) void*)g,
                                   (__attribute__((address_space(3))) void*)l, 16, 0, 0);
}
// fp8 e4m3 (OCP on gfx950) encode/decode via HW converts
__device__ inline unsigned char enc8(float v){
  return (unsigned char)(__builtin_amdgcn_cvt_pk_fp8_f32(v, v, 0, false) & 0xFF);
}
__device__ inline float2v dec8(unsigned u){
  return __builtin_amdgcn_cvt_pk_f32_fp8((int)u, false);   // decodes low 2 bytes
}

// ================= L1: fused front: [partition | convert-x stripe-frag | weight prep] ===========
__global__ __launch_bounds__(256) void fused_front(
    const float* __restrict__ x, int N, ushort* __restrict__ xb, int nstripe,
    const float* __restrict__ Wp, const float* __restrict__ Wl0, const float* __restrict__ Wr0,
    const float* __restrict__ Wl1, const float* __restrict__ Wr1, const float* __restrict__ W1,
    ushort* __restrict__ Wpf, ushort* __restrict__ Wl0f, ushort* __restrict__ Wr0f,
    ushort* __restrict__ Wl1f, ushort* __restrict__ Wr1f, ushort* __restrict__ W1f,
    const int* __restrict__ src, const int* __restrict__ dst, int E, int NB,
    int* __restrict__ bucketCnt, int* __restrict__ pairS, int* __restrict__ pairD,
    int nPart, int nConv)
{
  __shared__ int hist[NBMAX], lbase[NBMAX], gbase[NBMAX], lcur[NBMAX], sc[NBMAX];
  __shared__ int ls[EPB], ld[EPB];
  int bid = blockIdx.x;
  int t = threadIdx.x;

  if (bid < nPart){
    int base = bid * EPB;
    int cntE = E - base; if (cntE > EPB) cntE = EPB;
    for (int i=t;i<NB;i+=256) hist[i]=0;
    __syncthreads();
    int myS[JL], myD[JL];
    #pragma unroll
    for (int j=0;j<JL;j++){
      int e = base + j*256 + t;
      if (e < E){ myS[j]=src[e]; myD[j]=dst[e]; atomicAdd(&hist[myD[j]>>LOG_NPB],1); }
      else myD[j] = -1;
    }
    __syncthreads();
    if (t < NBMAX) sc[t] = (t < NB)? hist[t] : 0;
    __syncthreads();
    for (int st=1; st<NBMAX; st<<=1){
      int v = 0;
      if (t < NBMAX && t >= st) v = sc[t-st];
      __syncthreads();
      if (t < NBMAX) sc[t] += v;
      __syncthreads();
    }
    if (t < NB){
      int excl = (t>0)? sc[t-1] : 0;
      lbase[t] = excl; lcur[t] = excl;
      gbase[t] = atomicAdd(&bucketCnt[t], hist[t]);
    }
    __syncthreads();
    #pragma unroll
    for (int j=0;j<JL;j++){
      if (myD[j] >= 0){
        int b = myD[j] >> LOG_NPB;
        int p = atomicAdd(&lcur[b], 1);
        ls[p] = myS[j]; ld[p] = myD[j];
      }
    }
    __syncthreads();
    for (int i=t;i<cntE;i+=256){
      int d = ld[i];
      int b = d >> LOG_NPB;
      int p = gbase[b] + (i - lbase[b]);
      if (p < SLOTS){
        pairS[(size_t)b*SLOTS + p] = ls[i];
        pairD[(size_t)b*SLOTS + p] = d;
      }
    }
  } else if (bid < nPart + nConv){
    int gi = (bid - nPart)*256 + t;
    if (gi < nstripe*512){
      int L = gi & 63, ks = (gi>>6)&7, s = gi>>9;
      int row = s*16 + (L&15);
      int k = ks*32 + (L>>4)*8;
      short8 v;
      if (row < N){
        const float* p = x + (size_t)row*DIN + k;
        v = pack8(*(const float4*)p, *(const float4*)(p+4));
      } else {
        #pragma unroll
        for (int j=0;j<8;j++) v[j]=0;
      }
      *(short8*)(xb + (size_t)gi*8) = v;
    }
  } else {
    int gi = (bid - nPart - nConv)*256 + t;
    if (gi < 17408){
      const float* sw; ushort* dw; int cols, b0;
      if      (gi <  4096){ sw=Wp;  dw=Wpf;  cols=128; b0=0; }
      else if (gi <  8192){ sw=Wl0; dw=Wl0f; cols=128; b0=4096; }
      else if (gi < 12288){ sw=Wr0; dw=Wr0f; cols=128; b0=8192; }
      else if (gi < 14336){ sw=Wl1; dw=Wl1f; cols=128; b0=12288; }
      else if (gi < 16384){ sw=Wr1; dw=Wr1f; cols=128; b0=14336; }
      else                { sw=W1;  dw=W1f;  cols=64;  b0=16384; }
      int i = gi - b0;
      int ln = i & 63, g = i >> 6;
      int ntq = cols >> 4;
      int nt = g % ntq, ks = g / ntq;
      int col = nt*16 + (ln & 15);
      int k0 = ks*32 + (ln >> 4)*8;
      short8 v;
      #pragma unroll
      for (int j=0;j<8;j++) v[j] = (short)f2b(sw[(size_t)(k0+j)*cols + col]);
      *(short8*)(dw + (size_t)i*8) = v;
    }
  }
}

// ================= L2: [bucket_csr (padded-to-16, ushort adj) FIRST | GEMM0 wres] =================
__global__ __launch_bounds__(256) void gemm0_csr(
    const ushort* __restrict__ xb, int N, int nstripe, int ngemm, int nbuck,
    const ushort* __restrict__ Wpf, const ushort* __restrict__ Wl0f, const ushort* __restrict__ Wr0f,
    const float* __restrict__ bp,
    ushort* __restrict__ xp, unsigned char* __restrict__ q8lo, unsigned char* __restrict__ q8hi,
    ushort* __restrict__ xr0,
    const int* __restrict__ bucketCnt, const int* __restrict__ pairS, const int* __restrict__ pairD,
    int* __restrict__ off, int* __restrict__ deg, ushort* __restrict__ adj)
{
  __shared__ __align__(16) ushort smem[32768];
  int bid = blockIdx.x, t = threadIdx.x;

  if (bid >= nbuck){
    int g = bid - nbuck;
    int xcd = g & 7, jj = g >> 3;
    int mat = jj % 3;
    int b = xcd + 8*(jj/3);             // 3 mats of chunk-set b share bid%8 -> same XCD
    int nblk = ngemm / 3;
    const ushort* Wf = (mat==0)? Wpf : (mat==1)? Wl0f : Wr0f;
    int w = t>>6, lane = t&63, lq = lane&15, quad = lane>>4;
    #pragma unroll
    for (int j=0;j<16;j++){
      int gg = w + j*4;
      glds16(Wf + (size_t)gg*512 + lane*8, smem + gg*512);
    }
    __syncthreads();
    float bias[8];
    #pragma unroll
    for (int nt=0;nt<8;nt++) bias[nt] = (mat==0)? bp[nt*16 + lq] : 0.f;
    int nchunk = (nstripe + 3) >> 2;

#define LOADAV(AV, cc) do { \
    int stripe_ = (cc)*4 + w; \
    if (stripe_ < nstripe){ \
      _Pragma("unroll") \
      for (int ks=0;ks<8;ks++) \
        AV[ks] = *(const short8*)(xb + ((size_t)stripe_*8 + ks)*512 + lane*8); \
    } \
  } while(0)

#define COMPSTORE(AV, cc) do { \
    int stripe_ = (cc)*4 + w; \
    if (stripe_ < nstripe){ \
      int row0_ = stripe_*16; \
      float4v acc_[8]; \
      _Pragma("unroll") for (int nt=0;nt<8;nt++){ \
        _Pragma("unroll") for (int r=0;r<4;r++) acc_[nt][r]=0.f; } \
      _Pragma("unroll") for (int ks=0;ks<8;ks++){ \
        _Pragma("unroll") for (int nt=0;nt<8;nt++){ \
          short8 bf_ = *(const short8*)(smem + (size_t)((ks*8+nt)*64 + lane)*8); \
          acc_[nt] = __builtin_amdgcn_mfma_f32_16x16x32_bf16(AV[ks], bf_, acc_[nt], 0,0,0); \
        } \
      } \
      if (mat == 1){ \
        _Pragma("unroll") for (int nt=0;nt<8;nt++) \
        _Pragma("unroll") for (int r=0;r<4;r++){ \
          int row_ = row0_ + quad*4 + r; \
          if (row_ < N){ \
            if (nt < 4) q8lo[(size_t)row_*64 + nt*16 + lq] = enc8(acc_[nt][r]); \
            else        q8hi[(size_t)row_*64 + (nt-4)*16 + lq] = enc8(acc_[nt][r]); \
          } \
        } \
      } else { \
        ushort* Y_ = (mat==0)? xp : xr0; \
        _Pragma("unroll") for (int nt=0;nt<8;nt++) \
        _Pragma("unroll") for (int r=0;r<4;r++){ \
          int row_ = row0_ + quad*4 + r; \
          if (row_ < N) Y_[(size_t)row_*128 + nt*16 + lq] = f2b(acc_[nt][r] + bias[nt]); \
        } \
      } \
    } \
  } while(0)

    short8 avA[8], avB[8];
    int c = b;
    if (c < nchunk){
      LOADAV(avA, c);
      while (true){
        int cn = c + nblk;
        if (cn < nchunk) LOADAV(avB, cn);
        COMPSTORE(avA, c);
        c = cn;
        if (c >= nchunk) break;
        cn = c + nblk;
        if (cn < nchunk) LOADAV(avA, cn);
        COMPSTORE(avB, c);
        c = cn;
        if (c >= nchunk) break;
      }
    }
#undef LOADAV
#undef COMPSTORE
  } else {
    // -------- bucket CSR: 256 nodes/bucket, int4-vectorized walks, ushort adj --------
    int b = bid;
    int* cnt  = (int*)smem;             // [256]
    int* offl = cnt + 256;              // [257]
    int* s1   = offl + 257;             // [256]
    ushort* win = (ushort*)(s1 + 256);  // [<= SLOTS]
    int node0 = b * NPB;
    int base  = b * SLOTS;
    int ce = bucketCnt[b]; if (ce > SLOTS) ce = SLOTS;
    int ce4 = ce & ~3;
    cnt[t] = 0;
    __syncthreads();
    for (int i = t*4; i < ce4; i += 1024){
      int4 dd = *(const int4*)(pairD + base + i);
      atomicAdd(&cnt[dd.x - node0], 1);
      atomicAdd(&cnt[dd.y - node0], 1);
      atomicAdd(&cnt[dd.z - node0], 1);
      atomicAdd(&cnt[dd.w - node0], 1);
    }
    for (int i = ce4 + t; i < ce; i += 256)
      atomicAdd(&cnt[pairD[(size_t)base+i] - node0], 1);
    __syncthreads();
    int a = cnt[t];
    int pa = (a + 15) & ~15;         // padded count
    s1[t] = pa;
    __syncthreads();
    for (int st=1; st<256; st<<=1){
      int v = (t>=st)? s1[t-st] : 0;
      __syncthreads();
      s1[t] += v;
      __syncthreads();
    }
    int excl = (t>0)? s1[t-1] : 0;
    offl[t] = excl;
    int ptotal = s1[255]; if (ptotal > SLOTS) ptotal = SLOTS;
    int node = node0 + t;
    if (node < N){ off[node] = base + excl; deg[node] = a; }
    __syncthreads();
    for (int i=t;i<ptotal;i+=256) win[i] = (ushort)N;  // zero-row padding
    __syncthreads();
    for (int i = t*4; i < ce4; i += 1024){
      int4 dd = *(const int4*)(pairD + base + i);
      int4 ss = *(const int4*)(pairS + base + i);
      int p0 = atomicAdd(&offl[dd.x - node0], 1); if (p0 < SLOTS) win[p0] = (ushort)ss.x;
      int p1 = atomicAdd(&offl[dd.y - node0], 1); if (p1 < SLOTS) win[p1] = (ushort)ss.y;
      int p2 = atomicAdd(&offl[dd.z - node0], 1); if (p2 < SLOTS) win[p2] = (ushort)ss.z;
      int p3 = atomicAdd(&offl[dd.w - node0], 1); if (p3 < SLOTS) win[p3] = (ushort)ss.w;
    }
    for (int i = ce4 + t; i < ce; i += 256){
      int dd = pairD[(size_t)base+i];
      int p = atomicAdd(&offl[dd - node0], 1);
      if (p < SLOTS) win[p] = (ushort)pairS[(size_t)base+i];
    }
    __syncthreads();
    for (int i=t;i<ptotal;i+=256) adj[(size_t)base+i] = win[i];
  }
}

// ================= combine (one dim-half, half-wave packed rows) =================
// Grid = 2*nbh blocks: [0,nbh) gather q8lo (dims 0..63), [nbh,2nbh) q8hi.
// Wave owns 2 nodes; per 16-neighbor batch: 2 uniform uint4 adj loads + 8
// row-loads (lanes 0-31 -> neighbor 2j, lanes 32-63 -> neighbor 2j+1).
// shfl_xor(32) folds half-sums; half-wave 0 writes node A, 1 writes node B.
__global__ __launch_bounds__(256) void combine_f8h(
    const unsigned char* __restrict__ q8lo, const unsigned char* __restrict__ q8hi,
    const ushort* __restrict__ rootsrc, const ushort* __restrict__ ressrc,
    const float* __restrict__ bias,
    const int* __restrict__ off, const int* __restrict__ deg,
    const ushort* __restrict__ adj, ushort* __restrict__ out, int n, int nbh)
{
  int t = threadIdx.x, w = t>>6, lane = t&63;
  int sub = lane & 31, hi = lane >> 5;
  int b = blockIdx.x;
  int half = (b >= nbh) ? 1 : 0;
  int nA = (b - half*nbh)*8 + w*2, nB = nA + 1;
  if (nA >= n) return;
  const unsigned char* a8 = half ? q8hi : q8lo;
  bool vB = nB < n;
  int pA = off[nA], cA = deg[nA], eA = pA + ((cA + 15) & ~15);
  int pB = 0, cB = 0, eB = 0;
  if (vB){ pB = off[nB]; cB = deg[nB]; eB = pB + ((cB + 15) & ~15); }
  int boff = sub*2;          // byte offset of this lane's 2 dims in a 64B row
  int sh = hi << 4;          // 0 or 16: which ushort of each adj dword
  float2v aA = {0.f,0.f}, aB = {0.f,0.f};
  while (pA < eA || pB < eB){
    bool dA = pA < eA, dB = pB < eB;
    ushort uA[8], uB[8];
    if (dA){
      uint4 x0 = *(const uint4*)(adj + pA);
      uint4 x1 = *(const uint4*)(adj + pA + 8);
      unsigned wv[8] = {x0.x,x0.y,x0.z,x0.w,x1.x,x1.y,x1.z,x1.w};
      #pragma unroll
      for (int j=0;j<8;j++){
        unsigned ix = (wv[j] >> sh) & 0xffffu;
        uA[j] = *(const ushort*)(a8 + (size_t)ix*64 + boff);
      }
    }
    if (dB){
      uint4 x0 = *(const uint4*)(adj + pB);
      uint4 x1 = *(const uint4*)(adj + pB + 8);
      unsigned wv[8] = {x0.x,x0.y,x0.z,x0.w,x1.x,x1.y,x1.z,x1.w};
      #pragma unroll
      for (int j=0;j<8;j++){
        unsigned ix = (wv[j] >> sh) & 0xffffu;
        uB[j] = *(const ushort*)(a8 + (size_t)ix*64 + boff);
      }
    }
    if (dA){
      #pragma unroll
      for (int j=0;j<8;j++) aA += dec8(uA[j]);
      pA += 16;
    }
    if (dB){
      #pragma unroll
      for (int j=0;j<8;j++) aB += dec8(uB[j]);
      pB += 16;
    }
  }
  // fold the two half-wave partial sums (same dims, different neighbors)
  aA[0] += __shfl_xor(aA[0], 32);
  aA[1] += __shfl_xor(aA[1], 32);
  if (vB){
    aB[0] += __shfl_xor(aB[0], 32);
    aB[1] += __shfl_xor(aB[1], 32);
  }
  // epilogue: half-wave 0 -> node A, half-wave 1 -> node B
  int nodeT = hi ? nB : nA;
  int cT    = hi ? cB : cA;
  float s0  = hi ? aB[0] : aA[0];
  float s1v = hi ? aB[1] : aA[1];
  bool vT   = hi ? vB : true;
  if (vT){
    int hd = half*64 + boff;
    unsigned rt = *(const unsigned*)(rootsrc + (size_t)nodeT*128 + hd);
    unsigned rs = *(const unsigned*)(ressrc  + (size_t)nodeT*128 + hd);
    float2 bv = *(const float2*)(bias + hd);
    float inv = 1.f / (float)((cT > 1)? cT : 1);
    float o0 = fmaxf(s0 *inv + bv.x + blo(rt), 0.f) + blo(rs);
    float o1 = fmaxf(s1v*inv + bv.y + bhi(rt), 0.f) + bhi(rs);
    *(unsigned*)(out + (size_t)nodeT*128 + hd) = (unsigned)f2b(o0) | ((unsigned)f2b(o1) << 16);
  }
}

// ================= GEMM1: weights-resident; hl1 output fp8 (lo/hi), hr1 bf16 =================
__global__ __launch_bounds__(256) void gemm1_wres(
    const ushort* __restrict__ h, int N,
    const ushort* __restrict__ Wl1f, const ushort* __restrict__ Wr1f,
    unsigned char* __restrict__ q8lo, unsigned char* __restrict__ q8hi,
    ushort* __restrict__ hr1)
{
  __shared__ __align__(16) ushort Bs[32768];
  int t = threadIdx.x, w = t>>6, lane = t&63, lq = lane&15, quad = lane>>4;
  int tile = blockIdx.x;
  #pragma unroll
  for (int j=0;j<16;j++){
    int r = w + j*4;
    int m = r>>5, g = r&31;
    const ushort* Wm = m ? Wr1f : Wl1f;
    glds16(Wm + (size_t)g*512 + lane*8, Bs + r*512);
  }
  short8 av[2][4];
  int row0 = tile*128 + w*32;
  #pragma unroll
  for (int mt=0;mt<2;mt++){
    int row = row0 + mt*16 + lq; if (row >= N) row = N-1;
    #pragma unroll
    for (int ks=0;ks<4;ks++)
      av[mt][ks] = *(const short8*)(h + (size_t)row*128 + ks*32 + quad*8);
  }
  __syncthreads();
  #pragma unroll
  for (int m=0;m<2;m++){
    float4v acc[2][8];
    #pragma unroll
    for (int i=0;i<2;i++)
      #pragma unroll
      for (int j=0;j<8;j++)
        #pragma unroll
        for (int r=0;r<4;r++) acc[i][j][r] = 0.f;
    #pragma unroll
    for (int ks=0;ks<4;ks++){
      #pragma unroll
      for (int nt=0;nt<8;nt++){
        short8 bf = *(const short8*)(Bs + ((m*32 + ks*8 + nt)*64 + lane)*8);
        acc[0][nt] = __builtin_amdgcn_mfma_f32_16x16x32_bf16(av[0][ks], bf, acc[0][nt], 0,0,0);
        acc[1][nt] = __builtin_amdgcn_mfma_f32_16x16x32_bf16(av[1][ks], bf, acc[1][nt], 0,0,0);
      }
    }
    #pragma unroll
    for (int mt=0;mt<2;mt++){
      #pragma unroll
      for (int r=0;r<4;r++){
        int row = row0 + mt*16 + quad*4 + r;
        if (row < N){
          if (m == 0){
            #pragma unroll
            for (int nt=0;nt<8;nt++){
              if (nt < 4) q8lo[(size_t)row*64 + nt*16 + lq] = enc8(acc[mt][nt][r]);
              else        q8hi[(size_t)row*64 + (nt-4)*16 + lq] = enc8(acc[mt][nt][r]);
            }
          } else {
            #pragma unroll
            for (int nt=0;nt<8;nt++)
              hr1[(size_t)row*128 + nt*16 + lq] = f2b(acc[mt][nt][r]);
          }
        }
      }
    }
  }
}

// ================= head MLP: out = a*rer + (1-a)*(relu(h2@W1+b1)@W2+b2) =================
__global__ __launch_bounds__(256) void head_mlp(
    const ushort* __restrict__ h2, int n,
    const ushort* __restrict__ W1f, const float* __restrict__ b1,
    const float* __restrict__ W2, const float* __restrict__ b2,
    const float* __restrict__ alogit, const float* __restrict__ rer,
    float* __restrict__ out)
{
  __shared__ __align__(16) ushort W1s[8192];
  int t = threadIdx.x, w = t>>6, lane = t&63, lq = lane&15, quad = lane>>4;
  #pragma unroll
  for (int j=0;j<4;j++){
    int g = w + j*4;
    glds16(W1f + (size_t)g*512 + lane*8, W1s + g*512);
  }
  int row0 = blockIdx.x*128 + w*32;
  short8 av[2][4];
  #pragma unroll
  for (int mt=0;mt<2;mt++){
    int row = row0 + mt*16 + lq; if (row >= n) row = n-1;
    #pragma unroll
    for (int ks=0;ks<4;ks++)
      av[mt][ks] = *(const short8*)(h2 + (size_t)row*128 + ks*32 + quad*8);
  }
  __syncthreads();
  float4v acc[2][4];
  #pragma unroll
  for (int mt=0;mt<2;mt++)
    #pragma unroll
    for (int nt=0;nt<4;nt++)
      #pragma unroll
      for (int r=0;r<4;r++) acc[mt][nt][r] = 0.f;
  #pragma unroll
  for (int ks=0;ks<4;ks++){
    #pragma unroll
    for (int nt=0;nt<4;nt++){
      short8 bf = *(const short8*)(W1s + ((ks*4 + nt)*64 + lane)*8);
      acc[0][nt] = __builtin_amdgcn_mfma_f32_16x16x32_bf16(av[0][ks], bf, acc[0][nt], 0,0,0);
      acc[1][nt] = __builtin_amdgcn_mfma_f32_16x16x32_bf16(av[1][ks], bf, acc[1][nt], 0,0,0);
    }
  }
  float al = alogit[0];
  float a  = 1.f / (1.f + __expf(-al));
  #pragma unroll
  for (int mt=0;mt<2;mt++){
    float pw[4] = {0.f,0.f,0.f,0.f};
    #pragma unroll
    for (int nt=0; nt<4; nt++){
      int c = nt*16 + lq;
      float w2 = W2[c];
      float bb = b1[c];
      #pragma unroll
      for (int r=0; r<4; r++)
        pw[r] += fmaxf(acc[mt][nt][r] + bb, 0.f) * w2;
    }
    #pragma unroll
    for (int mask=1; mask<16; mask<<=1){
      #pragma unroll
      for (int r=0; r<4; r++)
        pw[r] += __shfl_xor(pw[r], mask);
    }
    if (lq == 0){
      #pragma unroll
      for (int r=0; r<4; r++){
        int row = row0 + mt*16 + quad*4 + r;
        if (row < n)
          out[row] = a * rer[row] + (1.f - a) * (pw[r] + b2[0]);
      }
    }
  }
}

extern "C" void kernel_launch(void* const* d_in, const int* in_sizes, int n_in,
                              void* d_out, int out_size, void* d_ws, size_t ws_size,
                              hipStream_t stream)
{
  (void)n_in; (void)out_size; (void)ws_size;
  const float* x    = (const float*)d_in[0];
  const int*   ei   = (const int*)d_in[1];
  const float* rer  = (const float*)d_in[2];
  const float* Wp   = (const float*)d_in[3];
  const float* bp   = (const float*)d_in[4];
  const float* Wl0  = (const float*)d_in[5];
  const float* bl0  = (const float*)d_in[6];
  const float* Wr0  = (const float*)d_in[7];
  const float* Wl1  = (const float*)d_in[8];
  const float* bl1  = (const float*)d_in[9];
  const float* Wr1  = (const float*)d_in[10];
  const float* W1   = (const float*)d_in[11];
  const float* b1   = (const float*)d_in[12];
  const float* W2   = (const float*)d_in[13];
  const float* b2   = (const float*)d_in[14];
  const float* alogit = (const float*)d_in[15];

  const int N = in_sizes[2];      // 50000
  const int E = in_sizes[1] / 2;  // 800000
  const int* src = ei;
  const int* dst = ei + E;
  const int NB = (N + NPB - 1) / NPB;        // 196
  const int nstripe = (N + 15) / 16;         // 3125
  const int ntile = (N + 127) / 128;         // 391
  const int nPart = (E + EPB - 1) / EPB;     // 391
  const int nConv = (nstripe*512 + 255)/256; // 6250
  const int nbh = (N + 7) / 8;               // 6250 blocks per dim-half

  // workspace layout (q8lo/q8hi have N+1 rows; row N is the zero row)
  ushort* U = (ushort*)d_ws;
  ushort* xb  = U;                           // stripe-frag x; reused as h2
  ushort* xp  = xb + (size_t)nstripe*512*8;  // [N][128] residual
  ushort* xr0 = xp  + (size_t)N*DH;          // root0; reused as hr1
  ushort* h   = xr0 + (size_t)N*DH;
  unsigned char* q8lo = (unsigned char*)(h + (size_t)N*DH);   // [N+1][64] fp8
  unsigned char* q8hi = q8lo + (size_t)(N+1)*64;              // [N+1][64] fp8
  ushort* Wpf  = (ushort*)(q8hi + (size_t)(N+1)*64);
  ushort* Wl0f = Wpf  + (size_t)4096*8;
  ushort* Wr0f = Wl0f + (size_t)4096*8;
  ushort* Wl1f = Wr0f + (size_t)4096*8;
  ushort* Wr1f = Wl1f + (size_t)2048*8;
  ushort* W1f  = Wr1f + (size_t)2048*8;
  int* I = (int*)(W1f + (size_t)1024*8);
  int* bucketCnt = I;
  int* off   = bucketCnt + NBMAX;
  int* deg   = off + N;
  int* pairS = deg + N;
  int* pairD = pairS + (size_t)NB*SLOTS;
  ushort* adj = (ushort*)(pairD + (size_t)NB*SLOTS);
  ushort* h2  = xb;                          // aliases xb (dead after GEMM0)

  hipMemsetAsync(bucketCnt, 0, NBMAX*sizeof(int), stream);
  hipMemsetAsync(q8lo + (size_t)N*64, 0, 64, stream);   // zero rows for padding
  hipMemsetAsync(q8hi + (size_t)N*64, 0, 64, stream);

  // L1: [partition | convert | prep]
  fused_front<<<nPart + nConv + 68, 256, 0, stream>>>(
      x, N, xb, nstripe, Wp, Wl0, Wr0, Wl1, Wr1, W1,
      Wpf, Wl0f, Wr0f, Wl1f, Wr1f, W1f,
      src, dst, E, NB, bucketCnt, pairS, pairD, nPart, nConv);

  // L2: [bucket_csr FIRST | GEMM0]  (xl0 -> q8lo/q8hi fp8; CSR padded to 16)
  gemm0_csr<<<NB + 768, 256, 0, stream>>>(
      xb, N, nstripe, 768, NB, Wpf, Wl0f, Wr0f, bp, xp, q8lo, q8hi, xr0,
      bucketCnt, pairS, pairD, off, deg, adj);

  // combine0 (two L2-resident passes): h = relu(mean(q8[nbrs]) + bl0 + xr0) + xp
  combine_f8h<<<2*nbh, 256, 0, stream>>>(q8lo, q8hi, xr0, xp, bl0, off, deg, adj, h, N, nbh);

  // GEMM1: hl1 -> q8lo/q8hi (fp8), hr1 -> xr0 (bf16)
  gemm1_wres<<<ntile, 256, 0, stream>>>(h, N, Wl1f, Wr1f, q8lo, q8hi, xr0);

  // combine1 (two passes): h2 = relu(mean(q8[nbrs]) + bl1 + hr1) + h
  combine_f8h<<<2*nbh, 256, 0, stream>>>(q8lo, q8hi, xr0, h, bl1, off, deg, adj, h2, N, nbh);

  // head MLP (dense)
  head_mlp<<<ntile, 256, 0, stream>>>(h2, N, W1f, b1, W2, b2, alogit, rer, (float*)d_out);
}

// Round 10
// 218.192 us; speedup vs baseline: 1.1560x; 1.0900x over previous
//
#include <hip/hip_runtime.h>
#include <hip/hip_bf16.h>

// SAGE reranker, round 19: REVERT to R15 (measured 218.5us — best).
// R16 (dim-split 2-pass), R17/R18 (half-wave packed L2-resident) all lost to
// this build: the combine gather is at max occupancy (48 VGPR, no LDS, 8
// waves/SIMD) with ~32 loads in flight/wave -> outstanding-miss slots are
// saturated; measured 46MB/~37us = ~1.25 TB/s is the random-access fabric
// ceiling (not the 1.8 streaming figure). Residency tricks lose because the
// per-pass streams (root/res/out) evict the gather array from the 4MB L2
// while adding issue overhead. R15 = empirical optimum of this decomposition:
// de-fused head, no-LDS combines, ushort adj, padded-16 CSR, fp8 aggregates.

#define DIN 256
#define DH 128
#define NPB 256
#define LOG_NPB 8
#define NBMAX 256
#define EPB 2048
#define JL (EPB/256)
#define SLOTS 8192

typedef __attribute__((ext_vector_type(8))) short short8;
typedef __attribute__((ext_vector_type(4))) float float4v;
typedef __attribute__((ext_vector_type(2))) float float2v;

__device__ inline ushort f2b(float f){
  unsigned u = __float_as_uint(f);
  u = (u + 0x7fffu + ((u >> 16) & 1u)) >> 16;   // round-nearest-even
  return (ushort)u;
}
__device__ inline float blo(unsigned v){ return __uint_as_float(v << 16); }
__device__ inline float bhi(unsigned v){ return __uint_as_float(v & 0xffff0000u); }
__device__ inline short8 pack8(float4 f0, float4 f1){
  short8 v;
  v[0]=(short)f2b(f0.x); v[1]=(short)f2b(f0.y); v[2]=(short)f2b(f0.z); v[3]=(short)f2b(f0.w);
  v[4]=(short)f2b(f1.x); v[5]=(short)f2b(f1.y); v[6]=(short)f2b(f1.z); v[7]=(short)f2b(f1.w);
  return v;
}
__device__ inline void glds16(const ushort* g, ushort* l){
  __builtin_amdgcn_global_load_lds((const __attribute__((address_space(1))) void*)g,
                                   (__attribute__((address_space(3))) void*)l, 16, 0, 0);
}
// fp8 e4m3 (OCP on gfx950) encode/decode via HW converts
__device__ inline unsigned char enc8(float v){
  return (unsigned char)(__builtin_amdgcn_cvt_pk_fp8_f32(v, v, 0, false) & 0xFF);
}
__device__ inline float2v dec8(unsigned u){
  return __builtin_amdgcn_cvt_pk_f32_fp8((int)u, false);   // decodes low 2 bytes
}

// Interleaved 2-node gather: padded CSR (pdeg multiple of 16, pad slots point
// at the zero row). Issue A's 16 loads, B's 16 loads, then accumulate A (B
// stays in flight), then B. Branch conditions are wave-uniform. Row indices
// go through readfirstlane -> scalar address pipe; accumulation is packed.
__device__ inline void gather16x2(const ushort* __restrict__ a8,
    const ushort* __restrict__ adj, int pA, int eA, int pB, int eB, int lane,
    float2v& aA, float2v& aB)
{
  while (pA < eA || pB < eB){
    ushort uA[16], uB[16];
    bool dA = pA < eA, dB = pB < eB;
    if (dA){
      #pragma unroll
      for (int j=0;j<16;j++){
        int ix = __builtin_amdgcn_readfirstlane((int)adj[pA+j]);
        uA[j] = a8[(size_t)ix*64 + lane];
      }
    }
    if (dB){
      #pragma unroll
      for (int j=0;j<16;j++){
        int ix = __builtin_amdgcn_readfirstlane((int)adj[pB+j]);
        uB[j] = a8[(size_t)ix*64 + lane];
      }
    }
    if (dA){
      #pragma unroll
      for (int j=0;j<16;j++) aA += dec8(uA[j]);
      pA += 16;
    }
    if (dB){
      #pragma unroll
      for (int j=0;j<16;j++) aB += dec8(uB[j]);
      pB += 16;
    }
  }
}

// ================= L1: fused front: [partition | convert-x stripe-frag | weight prep] ===========
__global__ __launch_bounds__(256) void fused_front(
    const float* __restrict__ x, int N, ushort* __restrict__ xb, int nstripe,
    const float* __restrict__ Wp, const float* __restrict__ Wl0, const float* __restrict__ Wr0,
    const float* __restrict__ Wl1, const float* __restrict__ Wr1, const float* __restrict__ W1,
    ushort* __restrict__ Wpf, ushort* __restrict__ Wl0f, ushort* __restrict__ Wr0f,
    ushort* __restrict__ Wl1f, ushort* __restrict__ Wr1f, ushort* __restrict__ W1f,
    const int* __restrict__ src, const int* __restrict__ dst, int E, int NB,
    int* __restrict__ bucketCnt, int* __restrict__ pairS, int* __restrict__ pairD,
    int nPart, int nConv)
{
  __shared__ int hist[NBMAX], lbase[NBMAX], gbase[NBMAX], lcur[NBMAX], sc[NBMAX];
  __shared__ int ls[EPB], ld[EPB];
  int bid = blockIdx.x;
  int t = threadIdx.x;

  if (bid < nPart){
    int base = bid * EPB;
    int cntE = E - base; if (cntE > EPB) cntE = EPB;
    for (int i=t;i<NB;i+=256) hist[i]=0;
    __syncthreads();
    int myS[JL], myD[JL];
    #pragma unroll
    for (int j=0;j<JL;j++){
      int e = base + j*256 + t;
      if (e < E){ myS[j]=src[e]; myD[j]=dst[e]; atomicAdd(&hist[myD[j]>>LOG_NPB],1); }
      else myD[j] = -1;
    }
    __syncthreads();
    if (t < NBMAX) sc[t] = (t < NB)? hist[t] : 0;
    __syncthreads();
    for (int st=1; st<NBMAX; st<<=1){
      int v = 0;
      if (t < NBMAX && t >= st) v = sc[t-st];
      __syncthreads();
      if (t < NBMAX) sc[t] += v;
      __syncthreads();
    }
    if (t < NB){
      int excl = (t>0)? sc[t-1] : 0;
      lbase[t] = excl; lcur[t] = excl;
      gbase[t] = atomicAdd(&bucketCnt[t], hist[t]);
    }
    __syncthreads();
    #pragma unroll
    for (int j=0;j<JL;j++){
      if (myD[j] >= 0){
        int b = myD[j] >> LOG_NPB;
        int p = atomicAdd(&lcur[b], 1);
        ls[p] = myS[j]; ld[p] = myD[j];
      }
    }
    __syncthreads();
    for (int i=t;i<cntE;i+=256){
      int d = ld[i];
      int b = d >> LOG_NPB;
      int p = gbase[b] + (i - lbase[b]);
      if (p < SLOTS){
        pairS[(size_t)b*SLOTS + p] = ls[i];
        pairD[(size_t)b*SLOTS + p] = d;
      }
    }
  } else if (bid < nPart + nConv){
    int gi = (bid - nPart)*256 + t;
    if (gi < nstripe*512){
      int L = gi & 63, ks = (gi>>6)&7, s = gi>>9;
      int row = s*16 + (L&15);
      int k = ks*32 + (L>>4)*8;
      short8 v;
      if (row < N){
        const float* p = x + (size_t)row*DIN + k;
        v = pack8(*(const float4*)p, *(const float4*)(p+4));
      } else {
        #pragma unroll
        for (int j=0;j<8;j++) v[j]=0;
      }
      *(short8*)(xb + (size_t)gi*8) = v;
    }
  } else {
    int gi = (bid - nPart - nConv)*256 + t;
    if (gi < 17408){
      const float* sw; ushort* dw; int cols, b0;
      if      (gi <  4096){ sw=Wp;  dw=Wpf;  cols=128; b0=0; }
      else if (gi <  8192){ sw=Wl0; dw=Wl0f; cols=128; b0=4096; }
      else if (gi < 12288){ sw=Wr0; dw=Wr0f; cols=128; b0=8192; }
      else if (gi < 14336){ sw=Wl1; dw=Wl1f; cols=128; b0=12288; }
      else if (gi < 16384){ sw=Wr1; dw=Wr1f; cols=128; b0=14336; }
      else                { sw=W1;  dw=W1f;  cols=64;  b0=16384; }
      int i = gi - b0;
      int ln = i & 63, g = i >> 6;
      int ntq = cols >> 4;
      int nt = g % ntq, ks = g / ntq;
      int col = nt*16 + (ln & 15);
      int k0 = ks*32 + (ln >> 4)*8;
      short8 v;
      #pragma unroll
      for (int j=0;j<8;j++) v[j] = (short)f2b(sw[(size_t)(k0+j)*cols + col]);
      *(short8*)(dw + (size_t)i*8) = v;
    }
  }
}

// ================= L2: [bucket_csr (padded-to-16, ushort adj) FIRST | GEMM0 wres] =================
__global__ __launch_bounds__(256) void gemm0_csr(
    const ushort* __restrict__ xb, int N, int nstripe, int ngemm, int nbuck,
    const ushort* __restrict__ Wpf, const ushort* __restrict__ Wl0f, const ushort* __restrict__ Wr0f,
    const float* __restrict__ bp,
    ushort* __restrict__ xp, unsigned char* __restrict__ q8, ushort* __restrict__ xr0,
    const int* __restrict__ bucketCnt, const int* __restrict__ pairS, const int* __restrict__ pairD,
    int* __restrict__ off, int* __restrict__ deg, ushort* __restrict__ adj)
{
  __shared__ __align__(16) ushort smem[32768];
  int bid = blockIdx.x, t = threadIdx.x;

  if (bid >= nbuck){
    int g = bid - nbuck;
    int xcd = g & 7, jj = g >> 3;
    int mat = jj % 3;
    int b = xcd + 8*(jj/3);             // 3 mats of chunk-set b share bid%8 -> same XCD
    int nblk = ngemm / 3;
    const ushort* Wf = (mat==0)? Wpf : (mat==1)? Wl0f : Wr0f;
    int w = t>>6, lane = t&63, lq = lane&15, quad = lane>>4;
    #pragma unroll
    for (int j=0;j<16;j++){
      int gg = w + j*4;
      glds16(Wf + (size_t)gg*512 + lane*8, smem + gg*512);
    }
    __syncthreads();
    float bias[8];
    #pragma unroll
    for (int nt=0;nt<8;nt++) bias[nt] = (mat==0)? bp[nt*16 + lq] : 0.f;
    int nchunk = (nstripe + 3) >> 2;

#define LOADAV(AV, cc) do { \
    int stripe_ = (cc)*4 + w; \
    if (stripe_ < nstripe){ \
      _Pragma("unroll") \
      for (int ks=0;ks<8;ks++) \
        AV[ks] = *(const short8*)(xb + ((size_t)stripe_*8 + ks)*512 + lane*8); \
    } \
  } while(0)

#define COMPSTORE(AV, cc) do { \
    int stripe_ = (cc)*4 + w; \
    if (stripe_ < nstripe){ \
      int row0_ = stripe_*16; \
      float4v acc_[8]; \
      _Pragma("unroll") for (int nt=0;nt<8;nt++){ \
        _Pragma("unroll") for (int r=0;r<4;r++) acc_[nt][r]=0.f; } \
      _Pragma("unroll") for (int ks=0;ks<8;ks++){ \
        _Pragma("unroll") for (int nt=0;nt<8;nt++){ \
          short8 bf_ = *(const short8*)(smem + (size_t)((ks*8+nt)*64 + lane)*8); \
          acc_[nt] = __builtin_amdgcn_mfma_f32_16x16x32_bf16(AV[ks], bf_, acc_[nt], 0,0,0); \
        } \
      } \
      if (mat == 1){ \
        _Pragma("unroll") for (int nt=0;nt<8;nt++) \
        _Pragma("unroll") for (int r=0;r<4;r++){ \
          int row_ = row0_ + quad*4 + r; \
          if (row_ < N) q8[(size_t)row_*128 + nt*16 + lq] = enc8(acc_[nt][r]); \
        } \
      } else { \
        ushort* Y_ = (mat==0)? xp : xr0; \
        _Pragma("unroll") for (int nt=0;nt<8;nt++) \
        _Pragma("unroll") for (int r=0;r<4;r++){ \
          int row_ = row0_ + quad*4 + r; \
          if (row_ < N) Y_[(size_t)row_*128 + nt*16 + lq] = f2b(acc_[nt][r] + bias[nt]); \
        } \
      } \
    } \
  } while(0)

    short8 avA[8], avB[8];
    int c = b;
    if (c < nchunk){
      LOADAV(avA, c);
      while (true){
        int cn = c + nblk;
        if (cn < nchunk) LOADAV(avB, cn);
        COMPSTORE(avA, c);
        c = cn;
        if (c >= nchunk) break;
        cn = c + nblk;
        if (cn < nchunk) LOADAV(avA, cn);
        COMPSTORE(avB, c);
        c = cn;
        if (c >= nchunk) break;
      }
    }
#undef LOADAV
#undef COMPSTORE
  } else {
    // -------- bucket CSR: 256 nodes/bucket, int4-vectorized walks, ushort adj --------
    int b = bid;
    int* cnt  = (int*)smem;             // [256]
    int* offl = cnt + 256;              // [257]
    int* s1   = offl + 257;             // [256]
    ushort* win = (ushort*)(s1 + 256);  // [<= SLOTS]
    int node0 = b * NPB;
    int base  = b * SLOTS;
    int ce = bucketCnt[b]; if (ce > SLOTS) ce = SLOTS;
    int ce4 = ce & ~3;
    cnt[t] = 0;
    __syncthreads();
    for (int i = t*4; i < ce4; i += 1024){
      int4 dd = *(const int4*)(pairD + base + i);
      atomicAdd(&cnt[dd.x - node0], 1);
      atomicAdd(&cnt[dd.y - node0], 1);
      atomicAdd(&cnt[dd.z - node0], 1);
      atomicAdd(&cnt[dd.w - node0], 1);
    }
    for (int i = ce4 + t; i < ce; i += 256)
      atomicAdd(&cnt[pairD[(size_t)base+i] - node0], 1);
    __syncthreads();
    int a = cnt[t];
    int pa = (a + 15) & ~15;         // padded count
    s1[t] = pa;
    __syncthreads();
    for (int st=1; st<256; st<<=1){
      int v = (t>=st)? s1[t-st] : 0;
      __syncthreads();
      s1[t] += v;
      __syncthreads();
    }
    int excl = (t>0)? s1[t-1] : 0;
    offl[t] = excl;
    int ptotal = s1[255]; if (ptotal > SLOTS) ptotal = SLOTS;
    int node = node0 + t;
    if (node < N){ off[node] = base + excl; deg[node] = a; }
    __syncthreads();
    for (int i=t;i<ptotal;i+=256) win[i] = (ushort)N;  // zero-row padding
    __syncthreads();
    for (int i = t*4; i < ce4; i += 1024){
      int4 dd = *(const int4*)(pairD + base + i);
      int4 ss = *(const int4*)(pairS + base + i);
      int p0 = atomicAdd(&offl[dd.x - node0], 1); if (p0 < SLOTS) win[p0] = (ushort)ss.x;
      int p1 = atomicAdd(&offl[dd.y - node0], 1); if (p1 < SLOTS) win[p1] = (ushort)ss.y;
      int p2 = atomicAdd(&offl[dd.z - node0], 1); if (p2 < SLOTS) win[p2] = (ushort)ss.z;
      int p3 = atomicAdd(&offl[dd.w - node0], 1); if (p3 < SLOTS) win[p3] = (ushort)ss.w;
    }
    for (int i = ce4 + t; i < ce; i += 256){
      int dd = pairD[(size_t)base+i];
      int p = atomicAdd(&offl[dd - node0], 1);
      if (p < SLOTS) win[p] = (ushort)pairS[(size_t)base+i];
    }
    __syncthreads();
    for (int i=t;i<ptotal;i+=256) adj[(size_t)base+i] = win[i];
  }
}

// ================= combine: out = bf16(relu(mean_fp8_agg + bias + root) + res) =================
// 2 nodes per wave, interleaved padded 16-deep gathers; no LDS, no barrier.
// Used TWICE: layer 0 (q8=xl0, root=xr0, res=xp -> h) and layer 1
// (q8=hl1, root=hr1, res=h -> h2).
__global__ __launch_bounds__(256) void combine0_f8(
    const unsigned char* __restrict__ agg8, const ushort* __restrict__ rootsrc,
    const ushort* __restrict__ ressrc, const float* __restrict__ bias,
    const int* __restrict__ off, const int* __restrict__ deg,
    const ushort* __restrict__ adj, ushort* __restrict__ out, int n)
{
  int t = threadIdx.x;
  int d = t & 63, w = t >> 6;
  int nA = blockIdx.x*8 + w*2, nB = nA + 1;
  if (nA >= n) return;
  const ushort* a8 = (const ushort*)agg8;
  bool vB = nB < n;
  unsigned rtA = ((const unsigned*)rootsrc)[(size_t)nA*64 + d];
  unsigned rsA = ((const unsigned*)ressrc)[(size_t)nA*64 + d];
  unsigned rtB = 0, rsB = 0;
  int pA = off[nA], cA = deg[nA], eA = pA + ((cA + 15) & ~15);
  int pB = 0, cB = 0, eB = 0;
  if (vB){
    rtB = ((const unsigned*)rootsrc)[(size_t)nB*64 + d];
    rsB = ((const unsigned*)ressrc)[(size_t)nB*64 + d];
    pB = off[nB]; cB = deg[nB]; eB = pB + ((cB + 15) & ~15);
  }
  float2v aA = {0.f, 0.f}, aB = {0.f, 0.f};
  gather16x2(a8, adj, pA, eA, pB, eB, d, aA, aB);
  float b0 = bias[2*d], b1v = bias[2*d+1];
  float invA = 1.f / (float)((cA > 1)? cA : 1);
  float o0 = fmaxf(aA[0]*invA + b0  + blo(rtA), 0.f) + blo(rsA);
  float o1 = fmaxf(aA[1]*invA + b1v + bhi(rtA), 0.f) + bhi(rsA);
  ((unsigned*)out)[(size_t)nA*64 + d] = (unsigned)f2b(o0) | ((unsigned)f2b(o1) << 16);
  if (vB){
    float invB = 1.f / (float)((cB > 1)? cB : 1);
    float q0 = fmaxf(aB[0]*invB + b0  + blo(rtB), 0.f) + blo(rsB);
    float q1 = fmaxf(aB[1]*invB + b1v + bhi(rtB), 0.f) + bhi(rsB);
    ((unsigned*)out)[(size_t)nB*64 + d] = (unsigned)f2b(q0) | ((unsigned)f2b(q1) << 16);
  }
}

// ================= GEMM1: weights-resident; hl1 output fp8, hr1 bf16 =================
__global__ __launch_bounds__(256) void gemm1_wres(
    const ushort* __restrict__ h, int N,
    const ushort* __restrict__ Wl1f, const ushort* __restrict__ Wr1f,
    unsigned char* __restrict__ q8, ushort* __restrict__ hr1)
{
  __shared__ __align__(16) ushort Bs[32768];
  int t = threadIdx.x, w = t>>6, lane = t&63, lq = lane&15, quad = lane>>4;
  int tile = blockIdx.x;
  #pragma unroll
  for (int j=0;j<16;j++){
    int r = w + j*4;
    int m = r>>5, g = r&31;
    const ushort* Wm = m ? Wr1f : Wl1f;
    glds16(Wm + (size_t)g*512 + lane*8, Bs + r*512);
  }
  short8 av[2][4];
  int row0 = tile*128 + w*32;
  #pragma unroll
  for (int mt=0;mt<2;mt++){
    int row = row0 + mt*16 + lq; if (row >= N) row = N-1;
    #pragma unroll
    for (int ks=0;ks<4;ks++)
      av[mt][ks] = *(const short8*)(h + (size_t)row*128 + ks*32 + quad*8);
  }
  __syncthreads();
  #pragma unroll
  for (int m=0;m<2;m++){
    float4v acc[2][8];
    #pragma unroll
    for (int i=0;i<2;i++)
      #pragma unroll
      for (int j=0;j<8;j++)
        #pragma unroll
        for (int r=0;r<4;r++) acc[i][j][r] = 0.f;
    #pragma unroll
    for (int ks=0;ks<4;ks++){
      #pragma unroll
      for (int nt=0;nt<8;nt++){
        short8 bf = *(const short8*)(Bs + ((m*32 + ks*8 + nt)*64 + lane)*8);
        acc[0][nt] = __builtin_amdgcn_mfma_f32_16x16x32_bf16(av[0][ks], bf, acc[0][nt], 0,0,0);
        acc[1][nt] = __builtin_amdgcn_mfma_f32_16x16x32_bf16(av[1][ks], bf, acc[1][nt], 0,0,0);
      }
    }
    #pragma unroll
    for (int mt=0;mt<2;mt++){
      #pragma unroll
      for (int r=0;r<4;r++){
        int row = row0 + mt*16 + quad*4 + r;
        if (row < N){
          if (m == 0){
            #pragma unroll
            for (int nt=0;nt<8;nt++)
              q8[(size_t)row*128 + nt*16 + lq] = enc8(acc[mt][nt][r]);
          } else {
            #pragma unroll
            for (int nt=0;nt<8;nt++)
              hr1[(size_t)row*128 + nt*16 + lq] = f2b(acc[mt][nt][r]);
          }
        }
      }
    }
  }
}

// ================= head MLP: out = a*rer + (1-a)*(relu(h2@W1+b1)@W2+b2) =================
// Dense over h2 [N][128] bf16. 128 rows/block, W1 in LDS.
__global__ __launch_bounds__(256) void head_mlp(
    const ushort* __restrict__ h2, int n,
    const ushort* __restrict__ W1f, const float* __restrict__ b1,
    const float* __restrict__ W2, const float* __restrict__ b2,
    const float* __restrict__ alogit, const float* __restrict__ rer,
    float* __restrict__ out)
{
  __shared__ __align__(16) ushort W1s[8192];
  int t = threadIdx.x, w = t>>6, lane = t&63, lq = lane&15, quad = lane>>4;
  #pragma unroll
  for (int j=0;j<4;j++){
    int g = w + j*4;
    glds16(W1f + (size_t)g*512 + lane*8, W1s + g*512);
  }
  int row0 = blockIdx.x*128 + w*32;
  short8 av[2][4];
  #pragma unroll
  for (int mt=0;mt<2;mt++){
    int row = row0 + mt*16 + lq; if (row >= n) row = n-1;
    #pragma unroll
    for (int ks=0;ks<4;ks++)
      av[mt][ks] = *(const short8*)(h2 + (size_t)row*128 + ks*32 + quad*8);
  }
  __syncthreads();
  float4v acc[2][4];
  #pragma unroll
  for (int mt=0;mt<2;mt++)
    #pragma unroll
    for (int nt=0;nt<4;nt++)
      #pragma unroll
      for (int r=0;r<4;r++) acc[mt][nt][r] = 0.f;
  #pragma unroll
  for (int ks=0;ks<4;ks++){
    #pragma unroll
    for (int nt=0;nt<4;nt++){
      short8 bf = *(const short8*)(W1s + ((ks*4 + nt)*64 + lane)*8);
      acc[0][nt] = __builtin_amdgcn_mfma_f32_16x16x32_bf16(av[0][ks], bf, acc[0][nt], 0,0,0);
      acc[1][nt] = __builtin_amdgcn_mfma_f32_16x16x32_bf16(av[1][ks], bf, acc[1][nt], 0,0,0);
    }
  }
  float al = alogit[0];
  float a  = 1.f / (1.f + __expf(-al));
  #pragma unroll
  for (int mt=0;mt<2;mt++){
    float pw[4] = {0.f,0.f,0.f,0.f};
    #pragma unroll
    for (int nt=0; nt<4; nt++){
      int c = nt*16 + lq;
      float w2 = W2[c];
      float bb = b1[c];
      #pragma unroll
      for (int r=0; r<4; r++)
        pw[r] += fmaxf(acc[mt][nt][r] + bb, 0.f) * w2;
    }
    #pragma unroll
    for (int mask=1; mask<16; mask<<=1){
      #pragma unroll
      for (int r=0; r<4; r++)
        pw[r] += __shfl_xor(pw[r], mask);
    }
    if (lq == 0){
      #pragma unroll
      for (int r=0; r<4; r++){
        int row = row0 + mt*16 + quad*4 + r;
        if (row < n)
          out[row] = a * rer[row] + (1.f - a) * (pw[r] + b2[0]);
      }
    }
  }
}

extern "C" void kernel_launch(void* const* d_in, const int* in_sizes, int n_in,
                              void* d_out, int out_size, void* d_ws, size_t ws_size,
                              hipStream_t stream)
{
  (void)n_in; (void)out_size; (void)ws_size;
  const float* x    = (const float*)d_in[0];
  const int*   ei   = (const int*)d_in[1];
  const float* rer  = (const float*)d_in[2];
  const float* Wp   = (const float*)d_in[3];
  const float* bp   = (const float*)d_in[4];
  const float* Wl0  = (const float*)d_in[5];
  const float* bl0  = (const float*)d_in[6];
  const float* Wr0  = (const float*)d_in[7];
  const float* Wl1  = (const float*)d_in[8];
  const float* bl1  = (const float*)d_in[9];
  const float* Wr1  = (const float*)d_in[10];
  const float* W1   = (const float*)d_in[11];
  const float* b1   = (const float*)d_in[12];
  const float* W2   = (const float*)d_in[13];
  const float* b2   = (const float*)d_in[14];
  const float* alogit = (const float*)d_in[15];

  const int N = in_sizes[2];      // 50000
  const int E = in_sizes[1] / 2;  // 800000
  const int* src = ei;
  const int* dst = ei + E;
  const int NB = (N + NPB - 1) / NPB;        // 196
  const int nstripe = (N + 15) / 16;         // 3125
  const int ntile = (N + 127) / 128;         // 391
  const int nPart = (E + EPB - 1) / EPB;     // 391
  const int nConv = (nstripe*512 + 255)/256; // 6250

  // workspace layout  (q8 has N+1 rows; row N is the zero row for padding)
  ushort* U = (ushort*)d_ws;
  ushort* xb  = U;                           // stripe-frag x; reused as h2 after GEMM0
  ushort* xp  = xb + (size_t)nstripe*512*8;  // [N][128] residual
  ushort* xr0 = xp  + (size_t)N*DH;          // root0; reused as hr1
  ushort* h   = xr0 + (size_t)N*DH;
  unsigned char* q8 = (unsigned char*)(h + (size_t)N*DH);  // [N+1][128] fp8 (xl0 then hl1)
  ushort* Wpf  = (ushort*)(q8 + (size_t)(N+1)*DH);
  ushort* Wl0f = Wpf  + (size_t)4096*8;
  ushort* Wr0f = Wl0f + (size_t)4096*8;
  ushort* Wl1f = Wr0f + (size_t)4096*8;
  ushort* Wr1f = Wl1f + (size_t)2048*8;
  ushort* W1f  = Wr1f + (size_t)2048*8;
  int* I = (int*)(W1f + (size_t)1024*8);
  int* bucketCnt = I;
  int* off   = bucketCnt + NBMAX;
  int* deg   = off + N;
  int* pairS = deg + N;
  int* pairD = pairS + (size_t)NB*SLOTS;
  ushort* adj = (ushort*)(pairD + (size_t)NB*SLOTS);
  ushort* h2  = xb;                          // aliases xb (dead after GEMM0)

  hipMemsetAsync(bucketCnt, 0, NBMAX*sizeof(int), stream);
  hipMemsetAsync(q8 + (size_t)N*DH, 0, DH, stream);   // zero row for padded slots

  // L1: [partition | convert | prep]
  fused_front<<<nPart + nConv + 68, 256, 0, stream>>>(
      x, N, xb, nstripe, Wp, Wl0, Wr0, Wl1, Wr1, W1,
      Wpf, Wl0f, Wr0f, Wl1f, Wr1f, W1f,
      src, dst, E, NB, bucketCnt, pairS, pairD, nPart, nConv);

  // L2: [bucket_csr FIRST | GEMM0]  (xl0 -> q8 fp8; CSR padded to 16)
  gemm0_csr<<<NB + 768, 256, 0, stream>>>(
      xb, N, nstripe, 768, NB, Wpf, Wl0f, Wr0f, bp, xp, q8, xr0,
      bucketCnt, pairS, pairD, off, deg, adj);

  // combine0: h = relu(mean_fp8(q8[nbrs]) + bl0 + xr0) + xp
  combine0_f8<<<(N+7)/8, 256, 0, stream>>>(q8, xr0, xp, bl0, off, deg, adj, h, N);

  // GEMM1: hl1 -> q8 (fp8), hr1 -> xr0 (bf16)
  gemm1_wres<<<ntile, 256, 0, stream>>>(h, N, Wl1f, Wr1f, q8, xr0);

  // combine1: h2 = relu(mean_fp8(q8[nbrs]) + bl1 + hr1) + h   (no LDS, max occupancy)
  combine0_f8<<<(N+7)/8, 256, 0, stream>>>(q8, xr0, h, bl1, off, deg, adj, h2, N);

  // head MLP (dense)
  head_mlp<<<ntile, 256, 0, stream>>>(h2, N, W1f, b1, W2, b2, alogit, rer, (float*)d_out);
}